// Round 14
// baseline (94.637 us; speedup 1.0000x reference)
//
#include <hip/hip_runtime.h>
#include <math.h>

#define GEO_N 256

__device__ __forceinline__ float frcp(float x) { return __builtin_amdgcn_rcpf(x); }
__device__ __forceinline__ float frsq(float x) { return __builtin_amdgcn_rsqf(x); }
__device__ __forceinline__ float fsqrtf_(float x) { return __builtin_amdgcn_sqrtf(x); }

__device__ __forceinline__ float wredf(float v) {
#pragma unroll
  for (int off = 32; off; off >>= 1) v += __shfl_xor(v, off, 64);
  return v;
}

// Null-space direction of (G - l*I) via max-norm cross product of rows. r13-validated.
__device__ __forceinline__ void eigvec3(float g00, float g01, float g02,
                                        float g11, float g12, float g22,
                                        float l, float v[3]) {
  const float m00 = g00 - l, m11 = g11 - l, m22 = g22 - l;
  const float a0 = g01 * g12 - g02 * m11, a1 = g02 * g01 - m00 * g12, a2 = m00 * m11 - g01 * g01;
  const float b0 = g01 * m22 - g02 * g12, b1 = g02 * g02 - m00 * m22, b2 = m00 * g12 - g01 * g02;
  const float c0 = m11 * m22 - g12 * g12, c1 = g12 * g02 - g01 * m22, c2 = g01 * g12 - m11 * g02;
  const float na = a0 * a0 + a1 * a1 + a2 * a2;
  const float nb = b0 * b0 + b1 * b1 + b2 * b2;
  const float nc = c0 * c0 + c1 * c1 + c2 * c2;
  float s0 = a0, s1 = a1, s2 = a2, ns = na;
  if (nb > ns) { s0 = b0; s1 = b1; s2 = b2; ns = nb; }
  if (nc > ns) { s0 = c0; s1 = c1; s2 = c2; ns = nc; }
  const bool bad = ns < 1e-28f;
  const float inv = frsq(fmaxf(ns, 1e-28f));
  v[0] = bad ? 1.0f : s0 * inv;
  v[1] = bad ? 0.0f : s1 * inv;
  v[2] = bad ? 0.0f : s2 * inv;
}

// Analytic closed-form solve (r13-validated, absmax 0.0): char-poly trisection
// eigenvalues, cross-of-rows eigenvectors, v1 skipped via completeness,
// R = A * (V diag(1/sigma) V^T).
__device__ __forceinline__ void solve_rst(const float s0in[16], float bc[13]) {
  const float invN = 1.0f / (float)GEO_N;
  const float smx = s0in[0] * invN, smy = s0in[1] * invN, smz = s0in[2] * invN;
  const float dmx = s0in[3] * invN, dmy = s0in[4] * invN, dmz = s0in[5] * invN;
  const float A00 = s0in[6] * invN - dmx * smx,  A01 = s0in[7] * invN - dmx * smy,  A02 = s0in[8] * invN - dmx * smz;
  const float A10 = s0in[9] * invN - dmy * smx,  A11 = s0in[10] * invN - dmy * smy, A12 = s0in[11] * invN - dmy * smz;
  const float A20 = s0in[12] * invN - dmz * smx, A21 = s0in[13] * invN - dmz * smy, A22 = s0in[14] * invN - dmz * smz;
  const float var_sum = s0in[15] * invN - (smx * smx + smy * smy + smz * smz);

  const float g00 = A00 * A00 + A10 * A10 + A20 * A20;
  const float g11 = A01 * A01 + A11 * A11 + A21 * A21;
  const float g22 = A02 * A02 + A12 * A12 + A22 * A22;
  const float g01 = A00 * A01 + A10 * A11 + A20 * A21;
  const float g02 = A00 * A02 + A10 * A12 + A20 * A22;
  const float g12 = A01 * A02 + A11 * A12 + A21 * A22;

  const float q = (g00 + g11 + g22) * (1.0f / 3.0f);
  const float c00 = g00 - q, c11 = g11 - q, c22 = g22 - q;
  const float p1 = g01 * g01 + g02 * g02 + g12 * g12;
  const float p2 = c00 * c00 + c11 * c11 + c22 * c22 + 2.0f * p1;
  const float p = fsqrtf_(p2 * (1.0f / 6.0f));
  const float pinv = frcp(fmaxf(p, 1e-20f));
  const float detC = c00 * (c11 * c22 - g12 * g12)
                   - g01 * (g01 * c22 - g12 * g02)
                   + g02 * (g01 * g12 - c11 * g02);
  float rr = 0.5f * detC * pinv * pinv * pinv;
  rr = fminf(1.0f, fmaxf(-1.0f, rr));
  const float arr = fabsf(rr);
  const float acs = fsqrtf_(fmaxf(1.0f - arr, 0.0f)) *
      (1.5707288f + arr * (-0.2121144f + arr * (0.0742610f + arr * (-0.0187293f))));
  const float acr = (rr >= 0.0f) ? acs : (3.14159265f - acs);
  const float phi = acr * (1.0f / 3.0f);
  const float x1 = phi * phi;
  const float cph = 1.0f + x1 * (-0.5f + x1 * ((1.0f / 24.0f) - x1 * (1.0f / 720.0f)));
  const float uu = 1.04719755f - phi;
  const float x2 = uu * uu;
  const float cp3 = -(1.0f + x2 * (-0.5f + x2 * ((1.0f / 24.0f) - x2 * (1.0f / 720.0f))));
  const float l0 = q + 2.0f * p * cph;
  const float l2 = q + 2.0f * p * cp3;
  const float l1 = 3.0f * q - l0 - l2;

  float v0[3], v2[3];
  eigvec3(g00, g01, g02, g11, g12, g22, l0, v0);
  eigvec3(g00, g01, g02, g11, g12, g22, l2, v2);

  const float sg0 = fsqrtf_(fmaxf(l0, 0.0f));
  const float sg1 = fsqrtf_(fmaxf(l1, 0.0f));
  const float sg2 = fsqrtf_(fmaxf(l2, 0.0f));
  const float iv0 = (sg0 > 1e-20f) ? frcp(sg0) : 0.0f;
  const float iv1 = (sg1 > 1e-20f) ? frcp(sg1) : 0.0f;
  const float iv2 = (sg2 > 1e-20f) ? frcp(sg2) : 0.0f;

  const float da = iv0 - iv1, db = iv2 - iv1;
  const float w00 = iv1 + da * v0[0] * v0[0] + db * v2[0] * v2[0];
  const float w11 = iv1 + da * v0[1] * v0[1] + db * v2[1] * v2[1];
  const float w22 = iv1 + da * v0[2] * v0[2] + db * v2[2] * v2[2];
  const float w01 = da * v0[0] * v0[1] + db * v2[0] * v2[1];
  const float w02 = da * v0[0] * v0[2] + db * v2[0] * v2[2];
  const float w12 = da * v0[1] * v0[2] + db * v2[1] * v2[2];

  const float R00 = A00 * w00 + A01 * w01 + A02 * w02;
  const float R01 = A00 * w01 + A01 * w11 + A02 * w12;
  const float R02 = A00 * w02 + A01 * w12 + A02 * w22;
  const float R10 = A10 * w00 + A11 * w01 + A12 * w02;
  const float R11 = A10 * w01 + A11 * w11 + A12 * w12;
  const float R12 = A10 * w02 + A11 * w12 + A12 * w22;
  const float R20 = A20 * w00 + A21 * w01 + A22 * w02;
  const float R21 = A20 * w01 + A21 * w11 + A22 * w12;
  const float R22 = A20 * w02 + A21 * w12 + A22 * w22;

  const float scale = (sg0 + sg1 + sg2) * frcp(fmaxf(var_sum, 1e-30f));
  bc[0] = R00; bc[1] = R01; bc[2] = R02;
  bc[3] = R10; bc[4] = R11; bc[5] = R12;
  bc[6] = R20; bc[7] = R21; bc[8] = R22;
  bc[9] = scale;
  bc[10] = dmx - scale * (R00 * smx + R01 * smy + R02 * smz);
  bc[11] = dmy - scale * (R10 * smx + R11 * smy + R12 * smz);
  bc[12] = dmz - scale * (R20 * smx + R21 * smy + R22 * smz);
}

// ---------- r13 structure + fused last-block final reduce. ----------
// Changes vs r13: (1) no early return (clamped wid + masked accumulate) so the
// end-of-kernel __syncthreads is uniform; (2) MOM(2)/MOM(3) share a scheduling
// region (their 17-stage shfl chains interleave); (3) int4 perm load; (4) block
// reduces its 4 wave sums in LDS -> ONE partial per block; last block (ticket
// counter, memset to 0 each call by host) reduces all block partials in fp64
// and writes out[0]. No separate reduce kernel.
__global__ __launch_bounds__(256) void geo_wave4f(const float* __restrict__ kp,
                                                  const int* __restrict__ perm,
                                                  float* __restrict__ partials,
                                                  unsigned int* __restrict__ counter,
                                                  float* __restrict__ out,
                                                  int B, int NW, double inv_total) {
  const int w = threadIdx.x >> 6, lane = threadIdx.x & 63;
  const int wid0 = blockIdx.x * 4 + w;
  const int wid = min(wid0, NW - 1);  // clamp; phantom waves masked below
  const int b0 = wid * 4;
  const float4* base = (const float4*)kp;

  int pm[4];
  if ((B & 3) == 0 && b0 + 3 < B) {
    const int4 pv = *(const int4*)(perm + b0);
    pm[0] = pv.x; pm[1] = pv.y; pm[2] = pv.z; pm[3] = pv.w;
  } else {
#pragma unroll
    for (int i = 0; i < 4; ++i) pm[i] = perm[min(b0 + i, B - 1)];
  }

  float4 S[4][3], D[4][3];
  float parked = 0.0f;

#define GEO_LOAD(i)                                                        \
  {                                                                        \
    const int bb = min(b0 + (i), B - 1);                                   \
    const float4* s4 = base + (size_t)bb * 192 + lane * 3;                 \
    const float4* d4 = base + (size_t)pm[(i)] * 192 + lane * 3;            \
    S[(i)][0] = s4[0]; S[(i)][1] = s4[1]; S[(i)][2] = s4[2];               \
    D[(i)][0] = d4[0]; D[(i)][1] = d4[1]; D[(i)][2] = d4[2];               \
  }

#define GEO_MOM(i)                                                         \
  {                                                                        \
    const float s_[12] = {S[(i)][0].x, S[(i)][0].y, S[(i)][0].z, S[(i)][0].w, \
                          S[(i)][1].x, S[(i)][1].y, S[(i)][1].z, S[(i)][1].w, \
                          S[(i)][2].x, S[(i)][2].y, S[(i)][2].z, S[(i)][2].w}; \
    const float d_[12] = {D[(i)][0].x, D[(i)][0].y, D[(i)][0].z, D[(i)][0].w, \
                          D[(i)][1].x, D[(i)][1].y, D[(i)][1].z, D[(i)][1].w, \
                          D[(i)][2].x, D[(i)][2].y, D[(i)][2].z, D[(i)][2].w}; \
    float r[16];                                                           \
    _Pragma("unroll") for (int k = 0; k < 16; ++k) r[k] = 0.0f;            \
    _Pragma("unroll") for (int p = 0; p < 4; ++p) {                        \
      const float sx = s_[3 * p + 0], sy = s_[3 * p + 1], sz = s_[3 * p + 2]; \
      const float dx = d_[3 * p + 0], dy = d_[3 * p + 1], dz = d_[3 * p + 2]; \
      r[0] += sx; r[1] += sy; r[2] += sz;                                  \
      r[3] += dx; r[4] += dy; r[5] += dz;                                  \
      r[6] += dx * sx; r[7] += dx * sy; r[8] += dx * sz;                   \
      r[9] += dy * sx; r[10] += dy * sy; r[11] += dy * sz;                 \
      r[12] += dz * sx; r[13] += dz * sy; r[14] += dz * sz;                \
      r[15] += sx * sx + sy * sy + sz * sz;                                \
    }                                                                      \
    const int b1 = lane & 1, b2 = (lane >> 1) & 1, b3 = (lane >> 2) & 1, b4 = (lane >> 3) & 1; \
    float v8[8], v4_[4], v2_[2], v1;                                       \
    _Pragma("unroll") for (int k = 0; k < 8; ++k) {                        \
      float send = b1 ? r[k] : r[k + 8];                                   \
      float recv = __shfl_xor(send, 1, 64);                                \
      v8[k] = (b1 ? r[k + 8] : r[k]) + recv;                               \
    }                                                                      \
    _Pragma("unroll") for (int k = 0; k < 4; ++k) {                        \
      float send = b2 ? v8[k] : v8[k + 4];                                 \
      float recv = __shfl_xor(send, 2, 64);                                \
      v4_[k] = (b2 ? v8[k + 4] : v8[k]) + recv;                            \
    }                                                                      \
    _Pragma("unroll") for (int k = 0; k < 2; ++k) {                        \
      float send = b3 ? v4_[k] : v4_[k + 2];                               \
      float recv = __shfl_xor(send, 4, 64);                                \
      v2_[k] = (b3 ? v4_[k + 2] : v4_[k]) + recv;                          \
    }                                                                      \
    {                                                                      \
      float send = b4 ? v2_[0] : v2_[1];                                   \
      float recv = __shfl_xor(send, 8, 64);                                \
      v1 = (b4 ? v2_[1] : v2_[0]) + recv;                                  \
    }                                                                      \
    v1 += __shfl_xor(v1, 16, 64);                                          \
    v1 += __shfl_xor(v1, 32, 64);                                          \
    if ((lane >> 4) == (i)) parked = v1;                                   \
  }

  // Pipelined schedule; final two moment phases share one region (chains interleave)
  GEO_LOAD(0)
  GEO_LOAD(1)
  __builtin_amdgcn_sched_barrier(0);
  GEO_MOM(0)
  GEO_LOAD(2)
  __builtin_amdgcn_sched_barrier(0);
  GEO_MOM(1)
  GEO_LOAD(3)
  __builtin_amdgcn_sched_barrier(0);
  GEO_MOM(2)
  GEO_MOM(3)

#undef GEO_LOAD
#undef GEO_MOM

  constexpr int br[16] = {0, 8, 4, 12, 2, 10, 6, 14, 1, 9, 5, 13, 3, 11, 7, 15};
  float s0[16];
#pragma unroll
  for (int k = 0; k < 16; ++k)
    s0[k] = __shfl(parked, ((lane & 3) << 4) | br[k], 64);

  float bc[13];
  solve_rst(s0, bc);

  float acc = 0.0f;
#pragma unroll
  for (int i = 0; i < 4; ++i) {
    const float R00 = __shfl(bc[0], i, 64), R01 = __shfl(bc[1], i, 64), R02 = __shfl(bc[2], i, 64);
    const float R10 = __shfl(bc[3], i, 64), R11 = __shfl(bc[4], i, 64), R12 = __shfl(bc[5], i, 64);
    const float R20 = __shfl(bc[6], i, 64), R21 = __shfl(bc[7], i, 64), R22 = __shfl(bc[8], i, 64);
    const float sc  = __shfl(bc[9], i, 64);
    const float Tx  = __shfl(bc[10], i, 64), Ty = __shfl(bc[11], i, 64), Tz = __shfl(bc[12], i, 64);
    const float s[12] = {S[i][0].x, S[i][0].y, S[i][0].z, S[i][0].w,
                         S[i][1].x, S[i][1].y, S[i][1].z, S[i][1].w,
                         S[i][2].x, S[i][2].y, S[i][2].z, S[i][2].w};
    const float d[12] = {D[i][0].x, D[i][0].y, D[i][0].z, D[i][0].w,
                         D[i][1].x, D[i][1].y, D[i][1].z, D[i][1].w,
                         D[i][2].x, D[i][2].y, D[i][2].z, D[i][2].w};
    float a = 0.0f;
#pragma unroll
    for (int q = 0; q < 4; ++q) {
      const float sx = s[3 * q + 0], sy = s[3 * q + 1], sz = s[3 * q + 2];
      const float dx = d[3 * q + 0], dy = d[3 * q + 1], dz = d[3 * q + 2];
      const float e0 = sc * (R00 * sx + R01 * sy + R02 * sz) + Tx - dx;
      const float e1 = sc * (R10 * sx + R11 * sy + R12 * sz) + Ty - dy;
      const float e2 = sc * (R20 * sx + R21 * sy + R22 * sz) + Tz - dz;
      a += fabsf(e0) + fabsf(e1) + fabsf(e2);
    }
    // mask: phantom waves (wid0 >= NW) and clamped tail batches contribute 0
    if (wid0 < NW && (size_t)wid0 * 4 + i < (size_t)B) acc += a;
  }
  acc = wredf(acc);

  // ---- Block reduce: 4 wave sums -> one partial ----
  __shared__ float lred[4];
  __shared__ unsigned int islast;
  if (lane == 0) lred[w] = acc;
  __syncthreads();
  if (threadIdx.x == 0) {
    partials[blockIdx.x] = (lred[0] + lred[1]) + (lred[2] + lred[3]);
    __threadfence();  // make partial visible device-wide before the ticket
    const unsigned int old = atomicAdd(counter, 1u);
    islast = (old == gridDim.x - 1) ? 1u : 0u;
  }
  __syncthreads();

  // ---- Last block: fp64 reduce of all block partials ----
  if (islast) {
    __threadfence();  // acquire side
    const int n = gridDim.x;
    double dacc = 0.0;
    for (int i = threadIdx.x; i < n; i += 256) dacc += (double)partials[i];
#pragma unroll
    for (int off = 32; off; off >>= 1) dacc += __shfl_xor(dacc, off, 64);
    __shared__ double sred[4];
    if (lane == 0) sred[w] = dacc;
    __syncthreads();
    if (threadIdx.x == 0)
      out[0] = (float)(((sred[0] + sred[1]) + (sred[2] + sred[3])) * inv_total);
  }
}

extern "C" void kernel_launch(void* const* d_in, const int* in_sizes, int n_in,
                              void* d_out, int out_size, void* d_ws, size_t ws_size,
                              hipStream_t stream) {
  const float* kp = (const float*)d_in[0];
  const int* perm = (const int*)d_in[1];
  float* out = (float*)d_out;
  const int B = in_sizes[1];
  const double inv_total = 1.0 / ((double)B * (double)GEO_N * 3.0);

  const int NW = (B + 3) / 4;        // one wave per 4 batches
  const int grid = (NW + 3) / 4;     // 4 waves per 256-thread block
  float* partials = (float*)d_ws;                       // grid floats
  unsigned int* counter = (unsigned int*)(partials + grid);  // 1 uint ticket

  hipMemsetAsync(counter, 0, sizeof(unsigned int), stream);
  geo_wave4f<<<grid, 256, 0, stream>>>(kp, perm, partials, counter, out,
                                       B, NW, inv_total);
}

// Round 15
// 55.966 us; speedup vs baseline: 1.6910x; 1.6910x over previous
//
#include <hip/hip_runtime.h>
#include <math.h>

#define GEO_N 256

__device__ __forceinline__ float frcp(float x) { return __builtin_amdgcn_rcpf(x); }
__device__ __forceinline__ float frsq(float x) { return __builtin_amdgcn_rsqf(x); }
__device__ __forceinline__ float fsqrtf_(float x) { return __builtin_amdgcn_sqrtf(x); }

// Non-temporal float4 load (emits nt flag — no L2 allocation; this workload
// is pure streaming, zero reuse).
typedef float f32x4 __attribute__((ext_vector_type(4)));
__device__ __forceinline__ float4 ntload4(const float4* p) {
  f32x4 v = __builtin_nontemporal_load((const f32x4*)p);
  return make_float4(v.x, v.y, v.z, v.w);
}

__device__ __forceinline__ float wredf(float v) {
#pragma unroll
  for (int off = 32; off; off >>= 1) v += __shfl_xor(v, off, 64);
  return v;
}

// Null-space direction of (G - l*I) via max-norm cross product of rows. r13-validated.
__device__ __forceinline__ void eigvec3(float g00, float g01, float g02,
                                        float g11, float g12, float g22,
                                        float l, float v[3]) {
  const float m00 = g00 - l, m11 = g11 - l, m22 = g22 - l;
  const float a0 = g01 * g12 - g02 * m11, a1 = g02 * g01 - m00 * g12, a2 = m00 * m11 - g01 * g01;
  const float b0 = g01 * m22 - g02 * g12, b1 = g02 * g02 - m00 * m22, b2 = m00 * g12 - g01 * g02;
  const float c0 = m11 * m22 - g12 * g12, c1 = g12 * g02 - g01 * m22, c2 = g01 * g12 - m11 * g02;
  const float na = a0 * a0 + a1 * a1 + a2 * a2;
  const float nb = b0 * b0 + b1 * b1 + b2 * b2;
  const float nc = c0 * c0 + c1 * c1 + c2 * c2;
  float s0 = a0, s1 = a1, s2 = a2, ns = na;
  if (nb > ns) { s0 = b0; s1 = b1; s2 = b2; ns = nb; }
  if (nc > ns) { s0 = c0; s1 = c1; s2 = c2; ns = nc; }
  const bool bad = ns < 1e-28f;
  const float inv = frsq(fmaxf(ns, 1e-28f));
  v[0] = bad ? 1.0f : s0 * inv;
  v[1] = bad ? 0.0f : s1 * inv;
  v[2] = bad ? 0.0f : s2 * inv;
}

// Analytic closed-form solve (r13-validated, absmax 0.0).
__device__ __forceinline__ void solve_rst(const float s0in[16], float bc[13]) {
  const float invN = 1.0f / (float)GEO_N;
  const float smx = s0in[0] * invN, smy = s0in[1] * invN, smz = s0in[2] * invN;
  const float dmx = s0in[3] * invN, dmy = s0in[4] * invN, dmz = s0in[5] * invN;
  const float A00 = s0in[6] * invN - dmx * smx,  A01 = s0in[7] * invN - dmx * smy,  A02 = s0in[8] * invN - dmx * smz;
  const float A10 = s0in[9] * invN - dmy * smx,  A11 = s0in[10] * invN - dmy * smy, A12 = s0in[11] * invN - dmy * smz;
  const float A20 = s0in[12] * invN - dmz * smx, A21 = s0in[13] * invN - dmz * smy, A22 = s0in[14] * invN - dmz * smz;
  const float var_sum = s0in[15] * invN - (smx * smx + smy * smy + smz * smz);

  const float g00 = A00 * A00 + A10 * A10 + A20 * A20;
  const float g11 = A01 * A01 + A11 * A11 + A21 * A21;
  const float g22 = A02 * A02 + A12 * A12 + A22 * A22;
  const float g01 = A00 * A01 + A10 * A11 + A20 * A21;
  const float g02 = A00 * A02 + A10 * A12 + A20 * A22;
  const float g12 = A01 * A02 + A11 * A12 + A21 * A22;

  const float q = (g00 + g11 + g22) * (1.0f / 3.0f);
  const float c00 = g00 - q, c11 = g11 - q, c22 = g22 - q;
  const float p1 = g01 * g01 + g02 * g02 + g12 * g12;
  const float p2 = c00 * c00 + c11 * c11 + c22 * c22 + 2.0f * p1;
  const float p = fsqrtf_(p2 * (1.0f / 6.0f));
  const float pinv = frcp(fmaxf(p, 1e-20f));
  const float detC = c00 * (c11 * c22 - g12 * g12)
                   - g01 * (g01 * c22 - g12 * g02)
                   + g02 * (g01 * g12 - c11 * g02);
  float rr = 0.5f * detC * pinv * pinv * pinv;
  rr = fminf(1.0f, fmaxf(-1.0f, rr));
  const float arr = fabsf(rr);
  const float acs = fsqrtf_(fmaxf(1.0f - arr, 0.0f)) *
      (1.5707288f + arr * (-0.2121144f + arr * (0.0742610f + arr * (-0.0187293f))));
  const float acr = (rr >= 0.0f) ? acs : (3.14159265f - acs);
  const float phi = acr * (1.0f / 3.0f);
  const float x1 = phi * phi;
  const float cph = 1.0f + x1 * (-0.5f + x1 * ((1.0f / 24.0f) - x1 * (1.0f / 720.0f)));
  const float uu = 1.04719755f - phi;
  const float x2 = uu * uu;
  const float cp3 = -(1.0f + x2 * (-0.5f + x2 * ((1.0f / 24.0f) - x2 * (1.0f / 720.0f))));
  const float l0 = q + 2.0f * p * cph;
  const float l2 = q + 2.0f * p * cp3;
  const float l1 = 3.0f * q - l0 - l2;

  float v0[3], v2[3];
  eigvec3(g00, g01, g02, g11, g12, g22, l0, v0);
  eigvec3(g00, g01, g02, g11, g12, g22, l2, v2);

  const float sg0 = fsqrtf_(fmaxf(l0, 0.0f));
  const float sg1 = fsqrtf_(fmaxf(l1, 0.0f));
  const float sg2 = fsqrtf_(fmaxf(l2, 0.0f));
  const float iv0 = (sg0 > 1e-20f) ? frcp(sg0) : 0.0f;
  const float iv1 = (sg1 > 1e-20f) ? frcp(sg1) : 0.0f;
  const float iv2 = (sg2 > 1e-20f) ? frcp(sg2) : 0.0f;

  const float da = iv0 - iv1, db = iv2 - iv1;
  const float w00 = iv1 + da * v0[0] * v0[0] + db * v2[0] * v2[0];
  const float w11 = iv1 + da * v0[1] * v0[1] + db * v2[1] * v2[1];
  const float w22 = iv1 + da * v0[2] * v0[2] + db * v2[2] * v2[2];
  const float w01 = da * v0[0] * v0[1] + db * v2[0] * v2[1];
  const float w02 = da * v0[0] * v0[2] + db * v2[0] * v2[2];
  const float w12 = da * v0[1] * v0[2] + db * v2[1] * v2[2];

  const float R00 = A00 * w00 + A01 * w01 + A02 * w02;
  const float R01 = A00 * w01 + A01 * w11 + A02 * w12;
  const float R02 = A00 * w02 + A01 * w12 + A02 * w22;
  const float R10 = A10 * w00 + A11 * w01 + A12 * w02;
  const float R11 = A10 * w01 + A11 * w11 + A12 * w12;
  const float R12 = A10 * w02 + A11 * w12 + A12 * w22;
  const float R20 = A20 * w00 + A21 * w01 + A22 * w02;
  const float R21 = A20 * w01 + A21 * w11 + A22 * w12;
  const float R22 = A20 * w02 + A21 * w12 + A22 * w22;

  const float scale = (sg0 + sg1 + sg2) * frcp(fmaxf(var_sum, 1e-30f));
  bc[0] = R00; bc[1] = R01; bc[2] = R02;
  bc[3] = R10; bc[4] = R11; bc[5] = R12;
  bc[6] = R20; bc[7] = R21; bc[8] = R22;
  bc[9] = scale;
  bc[10] = dmx - scale * (R00 * smx + R01 * smy + R02 * smz);
  bc[11] = dmy - scale * (R10 * smx + R11 * smy + R12 * smz);
  bc[12] = dmz - scale * (R20 * smx + R21 * smy + R22 * smz);
}

// ---------- r13 structure (interleaved loads, analytic solve, separate fin)
// + non-temporal point loads. ----------
__global__ __launch_bounds__(256) void geo_wave4p(const float* __restrict__ kp,
                                                  const int* __restrict__ perm,
                                                  float* __restrict__ partials,
                                                  int B, int NW) {
  const int wid = (blockIdx.x << 2) | (threadIdx.x >> 6);
  if (wid >= NW) return;  // no barriers in this kernel -> early return safe
  const int lane = threadIdx.x & 63;
  const int b0 = wid * 4;
  const float4* base = (const float4*)kp;

  int pm[4];
#pragma unroll
  for (int i = 0; i < 4; ++i) pm[i] = perm[min(b0 + i, B - 1)];

  float4 S[4][3], D[4][3];
  float parked = 0.0f;

#define GEO_LOAD(i)                                                        \
  {                                                                        \
    const int bb = min(b0 + (i), B - 1);                                   \
    const float4* s4 = base + (size_t)bb * 192 + lane * 3;                 \
    const float4* d4 = base + (size_t)pm[(i)] * 192 + lane * 3;            \
    S[(i)][0] = ntload4(s4 + 0); S[(i)][1] = ntload4(s4 + 1); S[(i)][2] = ntload4(s4 + 2); \
    D[(i)][0] = ntload4(d4 + 0); D[(i)][1] = ntload4(d4 + 1); D[(i)][2] = ntload4(d4 + 2); \
  }

#define GEO_MOM(i)                                                         \
  {                                                                        \
    const float s_[12] = {S[(i)][0].x, S[(i)][0].y, S[(i)][0].z, S[(i)][0].w, \
                          S[(i)][1].x, S[(i)][1].y, S[(i)][1].z, S[(i)][1].w, \
                          S[(i)][2].x, S[(i)][2].y, S[(i)][2].z, S[(i)][2].w}; \
    const float d_[12] = {D[(i)][0].x, D[(i)][0].y, D[(i)][0].z, D[(i)][0].w, \
                          D[(i)][1].x, D[(i)][1].y, D[(i)][1].z, D[(i)][1].w, \
                          D[(i)][2].x, D[(i)][2].y, D[(i)][2].z, D[(i)][2].w}; \
    float r[16];                                                           \
    _Pragma("unroll") for (int k = 0; k < 16; ++k) r[k] = 0.0f;            \
    _Pragma("unroll") for (int p = 0; p < 4; ++p) {                        \
      const float sx = s_[3 * p + 0], sy = s_[3 * p + 1], sz = s_[3 * p + 2]; \
      const float dx = d_[3 * p + 0], dy = d_[3 * p + 1], dz = d_[3 * p + 2]; \
      r[0] += sx; r[1] += sy; r[2] += sz;                                  \
      r[3] += dx; r[4] += dy; r[5] += dz;                                  \
      r[6] += dx * sx; r[7] += dx * sy; r[8] += dx * sz;                   \
      r[9] += dy * sx; r[10] += dy * sy; r[11] += dy * sz;                 \
      r[12] += dz * sx; r[13] += dz * sy; r[14] += dz * sz;                \
      r[15] += sx * sx + sy * sy + sz * sz;                                \
    }                                                                      \
    const int b1 = lane & 1, b2 = (lane >> 1) & 1, b3 = (lane >> 2) & 1, b4 = (lane >> 3) & 1; \
    float v8[8], v4_[4], v2_[2], v1;                                       \
    _Pragma("unroll") for (int k = 0; k < 8; ++k) {                        \
      float send = b1 ? r[k] : r[k + 8];                                   \
      float recv = __shfl_xor(send, 1, 64);                                \
      v8[k] = (b1 ? r[k + 8] : r[k]) + recv;                               \
    }                                                                      \
    _Pragma("unroll") for (int k = 0; k < 4; ++k) {                        \
      float send = b2 ? v8[k] : v8[k + 4];                                 \
      float recv = __shfl_xor(send, 2, 64);                                \
      v4_[k] = (b2 ? v8[k + 4] : v8[k]) + recv;                            \
    }                                                                      \
    _Pragma("unroll") for (int k = 0; k < 2; ++k) {                        \
      float send = b3 ? v4_[k] : v4_[k + 2];                               \
      float recv = __shfl_xor(send, 4, 64);                                \
      v2_[k] = (b3 ? v4_[k + 2] : v4_[k]) + recv;                          \
    }                                                                      \
    {                                                                      \
      float send = b4 ? v2_[0] : v2_[1];                                   \
      float recv = __shfl_xor(send, 8, 64);                                \
      v1 = (b4 ? v2_[1] : v2_[0]) + recv;                                  \
    }                                                                      \
    v1 += __shfl_xor(v1, 16, 64);                                          \
    v1 += __shfl_xor(v1, 32, 64);                                          \
    if ((lane >> 4) == (i)) parked = v1;                                   \
  }

  // ---- Pipelined schedule: loads interleaved with compute (r12/r13) ----
  GEO_LOAD(0)
  GEO_LOAD(1)
  __builtin_amdgcn_sched_barrier(0);
  GEO_MOM(0)
  GEO_LOAD(2)
  __builtin_amdgcn_sched_barrier(0);
  GEO_MOM(1)
  GEO_LOAD(3)
  __builtin_amdgcn_sched_barrier(0);
  GEO_MOM(2)
  __builtin_amdgcn_sched_barrier(0);
  GEO_MOM(3)

#undef GEO_LOAD
#undef GEO_MOM

  // ---- shfl-transpose: lane t gathers batch (t&3)'s 16 moments ----
  constexpr int br[16] = {0, 8, 4, 12, 2, 10, 6, 14, 1, 9, 5, 13, 3, 11, 7, 15};
  float s0[16];
#pragma unroll
  for (int k = 0; k < 16; ++k)
    s0[k] = __shfl(parked, ((lane & 3) << 4) | br[k], 64);

  // ---- One solve per wave (lane t solves batch b0 + (t&3)) ----
  float bc[13];
  solve_rst(s0, bc);

  // ---- Errors from live registers; params broadcast from lane i ----
  float acc = 0.0f;
#pragma unroll
  for (int i = 0; i < 4; ++i) {
    const float R00 = __shfl(bc[0], i, 64), R01 = __shfl(bc[1], i, 64), R02 = __shfl(bc[2], i, 64);
    const float R10 = __shfl(bc[3], i, 64), R11 = __shfl(bc[4], i, 64), R12 = __shfl(bc[5], i, 64);
    const float R20 = __shfl(bc[6], i, 64), R21 = __shfl(bc[7], i, 64), R22 = __shfl(bc[8], i, 64);
    const float sc  = __shfl(bc[9], i, 64);
    const float Tx  = __shfl(bc[10], i, 64), Ty = __shfl(bc[11], i, 64), Tz = __shfl(bc[12], i, 64);
    const float s[12] = {S[i][0].x, S[i][0].y, S[i][0].z, S[i][0].w,
                         S[i][1].x, S[i][1].y, S[i][1].z, S[i][1].w,
                         S[i][2].x, S[i][2].y, S[i][2].z, S[i][2].w};
    const float d[12] = {D[i][0].x, D[i][0].y, D[i][0].z, D[i][0].w,
                         D[i][1].x, D[i][1].y, D[i][1].z, D[i][1].w,
                         D[i][2].x, D[i][2].y, D[i][2].z, D[i][2].w};
    float a = 0.0f;
#pragma unroll
    for (int q = 0; q < 4; ++q) {
      const float sx = s[3 * q + 0], sy = s[3 * q + 1], sz = s[3 * q + 2];
      const float dx = d[3 * q + 0], dy = d[3 * q + 1], dz = d[3 * q + 2];
      const float e0 = sc * (R00 * sx + R01 * sy + R02 * sz) + Tx - dx;
      const float e1 = sc * (R10 * sx + R11 * sy + R12 * sz) + Ty - dy;
      const float e2 = sc * (R20 * sx + R21 * sy + R22 * sz) + Tz - dz;
      a += fabsf(e0) + fabsf(e1) + fabsf(e2);
    }
    if (b0 + i < B) acc += a;  // mask clamped tail batches
  }
  acc = wredf(acc);
  if (lane == 0) partials[wid] = acc;
}

// ---------- Final reduce ----------
__global__ __launch_bounds__(1024) void geo_fin(const float* __restrict__ partials,
                                                float* __restrict__ out, int n,
                                                double inv_total) {
  const int t = threadIdx.x;
  double acc = 0.0;
  for (int i = t; i < n; i += 1024) acc += (double)partials[i];
#pragma unroll
  for (int off = 32; off; off >>= 1) acc += __shfl_xor(acc, off, 64);
  __shared__ double sred[16];
  if ((t & 63) == 0) sred[t >> 6] = acc;
  __syncthreads();
  if (t == 0) {
    double tot = 0.0;
#pragma unroll
    for (int k = 0; k < 16; ++k) tot += sred[k];
    out[0] = (float)(tot * inv_total);
  }
}

extern "C" void kernel_launch(void* const* d_in, const int* in_sizes, int n_in,
                              void* d_out, int out_size, void* d_ws, size_t ws_size,
                              hipStream_t stream) {
  const float* kp = (const float*)d_in[0];
  const int* perm = (const int*)d_in[1];
  float* out = (float*)d_out;
  const int B = in_sizes[1];
  const double inv_total = 1.0 / ((double)B * (double)GEO_N * 3.0);

  const int NW = (B + 3) / 4;      // one wave per 4 batches
  float* partials = (float*)d_ws;  // NW floats
  const int grid = (NW + 3) / 4;   // 4 waves per 256-thread block
  geo_wave4p<<<grid, 256, 0, stream>>>(kp, perm, partials, B, NW);
  geo_fin<<<1, 1024, 0, stream>>>(partials, out, NW, inv_total);
}

// Round 16
// 40.202 us; speedup vs baseline: 2.3541x; 1.3921x over previous
//
#include <hip/hip_runtime.h>
#include <math.h>

#define GEO_N 256

__device__ __forceinline__ float frcp(float x) { return __builtin_amdgcn_rcpf(x); }
__device__ __forceinline__ float frsq(float x) { return __builtin_amdgcn_rsqf(x); }
__device__ __forceinline__ float fsqrtf_(float x) { return __builtin_amdgcn_sqrtf(x); }

__device__ __forceinline__ float wredf(float v) {
#pragma unroll
  for (int off = 32; off; off >>= 1) v += __shfl_xor(v, off, 64);
  return v;
}

// Null-space direction of (G - l*I) via max-norm cross product of rows. r13-validated.
__device__ __forceinline__ void eigvec3(float g00, float g01, float g02,
                                        float g11, float g12, float g22,
                                        float l, float v[3]) {
  const float m00 = g00 - l, m11 = g11 - l, m22 = g22 - l;
  const float a0 = g01 * g12 - g02 * m11, a1 = g02 * g01 - m00 * g12, a2 = m00 * m11 - g01 * g01;
  const float b0 = g01 * m22 - g02 * g12, b1 = g02 * g02 - m00 * m22, b2 = m00 * g12 - g01 * g02;
  const float c0 = m11 * m22 - g12 * g12, c1 = g12 * g02 - g01 * m22, c2 = g01 * g12 - m11 * g02;
  const float na = a0 * a0 + a1 * a1 + a2 * a2;
  const float nb = b0 * b0 + b1 * b1 + b2 * b2;
  const float nc = c0 * c0 + c1 * c1 + c2 * c2;
  float s0 = a0, s1 = a1, s2 = a2, ns = na;
  if (nb > ns) { s0 = b0; s1 = b1; s2 = b2; ns = nb; }
  if (nc > ns) { s0 = c0; s1 = c1; s2 = c2; ns = nc; }
  const bool bad = ns < 1e-28f;
  const float inv = frsq(fmaxf(ns, 1e-28f));
  v[0] = bad ? 1.0f : s0 * inv;
  v[1] = bad ? 0.0f : s1 * inv;
  v[2] = bad ? 0.0f : s2 * inv;
}

// Analytic closed-form solve (r13-validated, absmax 0.0).
__device__ __forceinline__ void solve_rst(const float s0in[16], float bc[13]) {
  const float invN = 1.0f / (float)GEO_N;
  const float smx = s0in[0] * invN, smy = s0in[1] * invN, smz = s0in[2] * invN;
  const float dmx = s0in[3] * invN, dmy = s0in[4] * invN, dmz = s0in[5] * invN;
  const float A00 = s0in[6] * invN - dmx * smx,  A01 = s0in[7] * invN - dmx * smy,  A02 = s0in[8] * invN - dmx * smz;
  const float A10 = s0in[9] * invN - dmy * smx,  A11 = s0in[10] * invN - dmy * smy, A12 = s0in[11] * invN - dmy * smz;
  const float A20 = s0in[12] * invN - dmz * smx, A21 = s0in[13] * invN - dmz * smy, A22 = s0in[14] * invN - dmz * smz;
  const float var_sum = s0in[15] * invN - (smx * smx + smy * smy + smz * smz);

  const float g00 = A00 * A00 + A10 * A10 + A20 * A20;
  const float g11 = A01 * A01 + A11 * A11 + A21 * A21;
  const float g22 = A02 * A02 + A12 * A12 + A22 * A22;
  const float g01 = A00 * A01 + A10 * A11 + A20 * A21;
  const float g02 = A00 * A02 + A10 * A12 + A20 * A22;
  const float g12 = A01 * A02 + A11 * A12 + A21 * A22;

  const float q = (g00 + g11 + g22) * (1.0f / 3.0f);
  const float c00 = g00 - q, c11 = g11 - q, c22 = g22 - q;
  const float p1 = g01 * g01 + g02 * g02 + g12 * g12;
  const float p2 = c00 * c00 + c11 * c11 + c22 * c22 + 2.0f * p1;
  const float p = fsqrtf_(p2 * (1.0f / 6.0f));
  const float pinv = frcp(fmaxf(p, 1e-20f));
  const float detC = c00 * (c11 * c22 - g12 * g12)
                   - g01 * (g01 * c22 - g12 * g02)
                   + g02 * (g01 * g12 - c11 * g02);
  float rr = 0.5f * detC * pinv * pinv * pinv;
  rr = fminf(1.0f, fmaxf(-1.0f, rr));
  const float arr = fabsf(rr);
  const float acs = fsqrtf_(fmaxf(1.0f - arr, 0.0f)) *
      (1.5707288f + arr * (-0.2121144f + arr * (0.0742610f + arr * (-0.0187293f))));
  const float acr = (rr >= 0.0f) ? acs : (3.14159265f - acs);
  const float phi = acr * (1.0f / 3.0f);
  const float x1 = phi * phi;
  const float cph = 1.0f + x1 * (-0.5f + x1 * ((1.0f / 24.0f) - x1 * (1.0f / 720.0f)));
  const float uu = 1.04719755f - phi;
  const float x2 = uu * uu;
  const float cp3 = -(1.0f + x2 * (-0.5f + x2 * ((1.0f / 24.0f) - x2 * (1.0f / 720.0f))));
  const float l0 = q + 2.0f * p * cph;
  const float l2 = q + 2.0f * p * cp3;
  const float l1 = 3.0f * q - l0 - l2;

  float v0[3], v2[3];
  eigvec3(g00, g01, g02, g11, g12, g22, l0, v0);
  eigvec3(g00, g01, g02, g11, g12, g22, l2, v2);

  const float sg0 = fsqrtf_(fmaxf(l0, 0.0f));
  const float sg1 = fsqrtf_(fmaxf(l1, 0.0f));
  const float sg2 = fsqrtf_(fmaxf(l2, 0.0f));
  const float iv0 = (sg0 > 1e-20f) ? frcp(sg0) : 0.0f;
  const float iv1 = (sg1 > 1e-20f) ? frcp(sg1) : 0.0f;
  const float iv2 = (sg2 > 1e-20f) ? frcp(sg2) : 0.0f;

  const float da = iv0 - iv1, db = iv2 - iv1;
  const float w00 = iv1 + da * v0[0] * v0[0] + db * v2[0] * v2[0];
  const float w11 = iv1 + da * v0[1] * v0[1] + db * v2[1] * v2[1];
  const float w22 = iv1 + da * v0[2] * v0[2] + db * v2[2] * v2[2];
  const float w01 = da * v0[0] * v0[1] + db * v2[0] * v2[1];
  const float w02 = da * v0[0] * v0[2] + db * v2[0] * v2[2];
  const float w12 = da * v0[1] * v0[2] + db * v2[1] * v2[2];

  const float R00 = A00 * w00 + A01 * w01 + A02 * w02;
  const float R01 = A00 * w01 + A01 * w11 + A02 * w12;
  const float R02 = A00 * w02 + A01 * w12 + A02 * w22;
  const float R10 = A10 * w00 + A11 * w01 + A12 * w02;
  const float R11 = A10 * w01 + A11 * w11 + A12 * w12;
  const float R12 = A10 * w02 + A11 * w12 + A12 * w22;
  const float R20 = A20 * w00 + A21 * w01 + A22 * w02;
  const float R21 = A20 * w01 + A21 * w11 + A22 * w12;
  const float R22 = A20 * w02 + A21 * w12 + A22 * w22;

  const float scale = (sg0 + sg1 + sg2) * frcp(fmaxf(var_sum, 1e-30f));
  bc[0] = R00; bc[1] = R01; bc[2] = R02;
  bc[3] = R10; bc[4] = R11; bc[5] = R12;
  bc[6] = R20; bc[7] = R21; bc[8] = R22;
  bc[9] = scale;
  bc[10] = dmx - scale * (R00 * smx + R01 * smy + R02 * smz);
  bc[11] = dmy - scale * (R10 * smx + R11 * smy + R12 * smz);
  bc[12] = dmz - scale * (R20 * smx + R21 * smy + R22 * smz);
}

// ---------- r13 structure + int4 perm load + merged MOM(2)/MOM(3) region.
// Default-cached loads (NT regressed: the dst gather is served by L2/L3 —
// FETCH stays at 1x input only because caches serve the second logical read).
__global__ __launch_bounds__(256) void geo_wave4p(const float* __restrict__ kp,
                                                  const int* __restrict__ perm,
                                                  float* __restrict__ partials,
                                                  int B, int NW) {
  const int wid = (blockIdx.x << 2) | (threadIdx.x >> 6);
  if (wid >= NW) return;  // no barriers in this kernel -> early return safe
  const int lane = threadIdx.x & 63;
  const int b0 = wid * 4;
  const float4* base = (const float4*)kp;

  int pm[4];
  if (b0 + 3 < B && (b0 & 3) == 0) {
    const int4 pv = *(const int4*)(perm + b0);  // one dwordx4 SMEM/VMEM op
    pm[0] = pv.x; pm[1] = pv.y; pm[2] = pv.z; pm[3] = pv.w;
  } else {
#pragma unroll
    for (int i = 0; i < 4; ++i) pm[i] = perm[min(b0 + i, B - 1)];
  }

  float4 S[4][3], D[4][3];
  float parked = 0.0f;

#define GEO_LOAD(i)                                                        \
  {                                                                        \
    const int bb = min(b0 + (i), B - 1);                                   \
    const float4* s4 = base + (size_t)bb * 192 + lane * 3;                 \
    const float4* d4 = base + (size_t)pm[(i)] * 192 + lane * 3;            \
    S[(i)][0] = s4[0]; S[(i)][1] = s4[1]; S[(i)][2] = s4[2];               \
    D[(i)][0] = d4[0]; D[(i)][1] = d4[1]; D[(i)][2] = d4[2];               \
  }

#define GEO_MOM(i)                                                         \
  {                                                                        \
    const float s_[12] = {S[(i)][0].x, S[(i)][0].y, S[(i)][0].z, S[(i)][0].w, \
                          S[(i)][1].x, S[(i)][1].y, S[(i)][1].z, S[(i)][1].w, \
                          S[(i)][2].x, S[(i)][2].y, S[(i)][2].z, S[(i)][2].w}; \
    const float d_[12] = {D[(i)][0].x, D[(i)][0].y, D[(i)][0].z, D[(i)][0].w, \
                          D[(i)][1].x, D[(i)][1].y, D[(i)][1].z, D[(i)][1].w, \
                          D[(i)][2].x, D[(i)][2].y, D[(i)][2].z, D[(i)][2].w}; \
    float r[16];                                                           \
    _Pragma("unroll") for (int k = 0; k < 16; ++k) r[k] = 0.0f;            \
    _Pragma("unroll") for (int p = 0; p < 4; ++p) {                        \
      const float sx = s_[3 * p + 0], sy = s_[3 * p + 1], sz = s_[3 * p + 2]; \
      const float dx = d_[3 * p + 0], dy = d_[3 * p + 1], dz = d_[3 * p + 2]; \
      r[0] += sx; r[1] += sy; r[2] += sz;                                  \
      r[3] += dx; r[4] += dy; r[5] += dz;                                  \
      r[6] += dx * sx; r[7] += dx * sy; r[8] += dx * sz;                   \
      r[9] += dy * sx; r[10] += dy * sy; r[11] += dy * sz;                 \
      r[12] += dz * sx; r[13] += dz * sy; r[14] += dz * sz;                \
      r[15] += sx * sx + sy * sy + sz * sz;                                \
    }                                                                      \
    const int b1 = lane & 1, b2 = (lane >> 1) & 1, b3 = (lane >> 2) & 1, b4 = (lane >> 3) & 1; \
    float v8[8], v4_[4], v2_[2], v1;                                       \
    _Pragma("unroll") for (int k = 0; k < 8; ++k) {                        \
      float send = b1 ? r[k] : r[k + 8];                                   \
      float recv = __shfl_xor(send, 1, 64);                                \
      v8[k] = (b1 ? r[k + 8] : r[k]) + recv;                               \
    }                                                                      \
    _Pragma("unroll") for (int k = 0; k < 4; ++k) {                        \
      float send = b2 ? v8[k] : v8[k + 4];                                 \
      float recv = __shfl_xor(send, 2, 64);                                \
      v4_[k] = (b2 ? v8[k + 4] : v8[k]) + recv;                            \
    }                                                                      \
    _Pragma("unroll") for (int k = 0; k < 2; ++k) {                        \
      float send = b3 ? v4_[k] : v4_[k + 2];                               \
      float recv = __shfl_xor(send, 4, 64);                                \
      v2_[k] = (b3 ? v4_[k + 2] : v4_[k]) + recv;                          \
    }                                                                      \
    {                                                                      \
      float send = b4 ? v2_[0] : v2_[1];                                   \
      float recv = __shfl_xor(send, 8, 64);                                \
      v1 = (b4 ? v2_[1] : v2_[0]) + recv;                                  \
    }                                                                      \
    v1 += __shfl_xor(v1, 16, 64);                                          \
    v1 += __shfl_xor(v1, 32, 64);                                          \
    if ((lane >> 4) == (i)) parked = v1;                                   \
  }

  // ---- Pipelined schedule; final two moment phases share one region so
  // their independent shfl chains interleave ----
  GEO_LOAD(0)
  GEO_LOAD(1)
  __builtin_amdgcn_sched_barrier(0);
  GEO_MOM(0)
  GEO_LOAD(2)
  __builtin_amdgcn_sched_barrier(0);
  GEO_MOM(1)
  GEO_LOAD(3)
  __builtin_amdgcn_sched_barrier(0);
  GEO_MOM(2)
  GEO_MOM(3)

#undef GEO_LOAD
#undef GEO_MOM

  // ---- shfl-transpose: lane t gathers batch (t&3)'s 16 moments ----
  constexpr int br[16] = {0, 8, 4, 12, 2, 10, 6, 14, 1, 9, 5, 13, 3, 11, 7, 15};
  float s0[16];
#pragma unroll
  for (int k = 0; k < 16; ++k)
    s0[k] = __shfl(parked, ((lane & 3) << 4) | br[k], 64);

  // ---- One solve per wave (lane t solves batch b0 + (t&3)) ----
  float bc[13];
  solve_rst(s0, bc);

  // ---- Errors from live registers; params broadcast from lane i ----
  float acc = 0.0f;
#pragma unroll
  for (int i = 0; i < 4; ++i) {
    const float R00 = __shfl(bc[0], i, 64), R01 = __shfl(bc[1], i, 64), R02 = __shfl(bc[2], i, 64);
    const float R10 = __shfl(bc[3], i, 64), R11 = __shfl(bc[4], i, 64), R12 = __shfl(bc[5], i, 64);
    const float R20 = __shfl(bc[6], i, 64), R21 = __shfl(bc[7], i, 64), R22 = __shfl(bc[8], i, 64);
    const float sc  = __shfl(bc[9], i, 64);
    const float Tx  = __shfl(bc[10], i, 64), Ty = __shfl(bc[11], i, 64), Tz = __shfl(bc[12], i, 64);
    const float s[12] = {S[i][0].x, S[i][0].y, S[i][0].z, S[i][0].w,
                         S[i][1].x, S[i][1].y, S[i][1].z, S[i][1].w,
                         S[i][2].x, S[i][2].y, S[i][2].z, S[i][2].w};
    const float d[12] = {D[i][0].x, D[i][0].y, D[i][0].z, D[i][0].w,
                         D[i][1].x, D[i][1].y, D[i][1].z, D[i][1].w,
                         D[i][2].x, D[i][2].y, D[i][2].z, D[i][2].w};
    float a = 0.0f;
#pragma unroll
    for (int q = 0; q < 4; ++q) {
      const float sx = s[3 * q + 0], sy = s[3 * q + 1], sz = s[3 * q + 2];
      const float dx = d[3 * q + 0], dy = d[3 * q + 1], dz = d[3 * q + 2];
      const float e0 = sc * (R00 * sx + R01 * sy + R02 * sz) + Tx - dx;
      const float e1 = sc * (R10 * sx + R11 * sy + R12 * sz) + Ty - dy;
      const float e2 = sc * (R20 * sx + R21 * sy + R22 * sz) + Tz - dz;
      a += fabsf(e0) + fabsf(e1) + fabsf(e2);
    }
    if (b0 + i < B) acc += a;  // mask clamped tail batches
  }
  acc = wredf(acc);
  if (lane == 0) partials[wid] = acc;
}

// ---------- Final reduce ----------
__global__ __launch_bounds__(1024) void geo_fin(const float* __restrict__ partials,
                                                float* __restrict__ out, int n,
                                                double inv_total) {
  const int t = threadIdx.x;
  double acc = 0.0;
  for (int i = t; i < n; i += 1024) acc += (double)partials[i];
#pragma unroll
  for (int off = 32; off; off >>= 1) acc += __shfl_xor(acc, off, 64);
  __shared__ double sred[16];
  if ((t & 63) == 0) sred[t >> 6] = acc;
  __syncthreads();
  if (t == 0) {
    double tot = 0.0;
#pragma unroll
    for (int k = 0; k < 16; ++k) tot += sred[k];
    out[0] = (float)(tot * inv_total);
  }
}

extern "C" void kernel_launch(void* const* d_in, const int* in_sizes, int n_in,
                              void* d_out, int out_size, void* d_ws, size_t ws_size,
                              hipStream_t stream) {
  const float* kp = (const float*)d_in[0];
  const int* perm = (const int*)d_in[1];
  float* out = (float*)d_out;
  const int B = in_sizes[1];
  const double inv_total = 1.0 / ((double)B * (double)GEO_N * 3.0);

  const int NW = (B + 3) / 4;      // one wave per 4 batches
  float* partials = (float*)d_ws;  // NW floats
  const int grid = (NW + 3) / 4;   // 4 waves per 256-thread block
  geo_wave4p<<<grid, 256, 0, stream>>>(kp, perm, partials, B, NW);
  geo_fin<<<1, 1024, 0, stream>>>(partials, out, NW, inv_total);
}